// Round 4
// baseline (288.294 us; speedup 1.0000x reference)
//
#include <hip/hip_runtime.h>

// INT4 symmetric dequant — ROUND 4: in-bench A/B of cache policy.
// Kernel A = round-3 winner (non-temporal loads+stores, contiguous layout).
// Kernel B = identical except fully cached (no nt). B runs second and
// overwrites d_out with bit-identical values -> output still exact.
// dur = C + K_nt + K_cached; vs round-3's C + K_nt = 235.4 us, so
// K_cached = dur - 235.4. Decides which policy ships in round 5.
//
// Memory floor: 90 MB packed read + 1.4 MB scale + 180 MB fp32 write
// = 272 MB -> ~45-50 us at mixed-stream achievable BW.

#define TOTAL_ELEMS (4096 * 86 * 128)        // 45,088,768
#define NQUADS (TOTAL_ELEMS / 4)             // 11,272,192 float4s
#define NTHREADS (NQUADS / 2)                // 5,636,096
#define NBLOCKS (NTHREADS / 256)             // 22016 exactly

typedef int   v2i __attribute__((ext_vector_type(2)));
typedef float v4f __attribute__((ext_vector_type(4)));

__device__ __forceinline__ void dequant8(v2i a, float s, v4f& o) {
    o.x = (float)((a.x & 15) - 8) * s;
    o.y = (float)((a.x >> 4) - 8) * s;
    o.z = (float)((a.y & 15) - 8) * s;
    o.w = (float)((a.y >> 4) - 8) * s;
}

// ---- A: non-temporal (round-3 behavior) ----
__global__ __launch_bounds__(256) void int4_dequant_nt(
    const v2i* __restrict__ packed, const float* __restrict__ scale,
    v4f* __restrict__ out)
{
    const int t = blockIdx.x * 256 + threadIdx.x;
    const int lane = t & 63;
    const int q0 = ((t & ~63) << 1) + lane;
    const int q1 = q0 + 64;

    v2i a = __builtin_nontemporal_load(&packed[q0]);
    v2i b = __builtin_nontemporal_load(&packed[q1]);
    const float s0 = scale[q0 >> 5];
    const float s1 = scale[q1 >> 5];

    v4f o0, o1;
    dequant8(a, s0, o0);
    dequant8(b, s1, o1);

    __builtin_nontemporal_store(o0, &out[q0]);
    __builtin_nontemporal_store(o1, &out[q1]);
}

// ---- B: fully cached, same layout ----
__global__ __launch_bounds__(256) void int4_dequant_cached(
    const v2i* __restrict__ packed, const float* __restrict__ scale,
    v4f* __restrict__ out)
{
    const int t = blockIdx.x * 256 + threadIdx.x;
    const int lane = t & 63;
    const int q0 = ((t & ~63) << 1) + lane;
    const int q1 = q0 + 64;

    v2i a = packed[q0];
    v2i b = packed[q1];
    const float s0 = scale[q0 >> 5];
    const float s1 = scale[q1 >> 5];

    v4f o0, o1;
    dequant8(a, s0, o0);
    dequant8(b, s1, o1);

    out[q0] = o0;
    out[q1] = o1;
}

extern "C" void kernel_launch(void* const* d_in, const int* in_sizes, int n_in,
                              void* d_out, int out_size, void* d_ws, size_t ws_size,
                              hipStream_t stream) {
    const v2i*   packed = (const v2i*)d_in[0];
    const float* scale  = (const float*)d_in[1];
    v4f*         out    = (v4f*)d_out;

    int4_dequant_nt<<<NBLOCKS, 256, 0, stream>>>(packed, scale, out);
    int4_dequant_cached<<<NBLOCKS, 256, 0, stream>>>(packed, scale, out);
}

// Round 5
// 244.020 us; speedup vs baseline: 1.1814x; 1.1814x over previous
//
#include <hip/hip_runtime.h>

// INT4 symmetric weight dequant: packed uint8-in-int32 nibbles -> fp32,
// per-(row,group) scale. OUT=4096, GROUPS=86, GSIZE=128.
//
// R4 A/B verdict: fully-cached beats non-temporal by ~1.7x on gfx950
// (K_cached = 52.9 us vs K_nt ~ 90 us; nt defeats LLC write-back
// combining for the 180 MB output stream). Ship cached.
//
// Memory: 90 MB packed read + 1.4 MB scale + 180 MB fp32 write = 272 MB
// -> 52.9 us = ~5.1 TB/s mixed-stream, near achievable ceiling.
//
// Layout: every memory instruction perfectly contiguous across the wave:
// lane l handles quads (wave_base + l) and (wave_base + 64 + l).
// All 4 outputs of a quad share one scale (group = 128 contiguous elems,
// 32 quads/group); 32 consecutive lanes share a scale -> L1-served.

#define TOTAL_ELEMS (4096 * 86 * 128)        // 45,088,768
#define NQUADS (TOTAL_ELEMS / 4)             // 11,272,192 float4s
#define NTHREADS (NQUADS / 2)                // 5,636,096
#define NBLOCKS (NTHREADS / 256)             // 22016 exactly

typedef int   v2i __attribute__((ext_vector_type(2)));
typedef float v4f __attribute__((ext_vector_type(4)));

__device__ __forceinline__ void dequant8(v2i a, float s, v4f& o) {
    o.x = (float)((a.x & 15) - 8) * s;
    o.y = (float)((a.x >> 4) - 8) * s;
    o.z = (float)((a.y & 15) - 8) * s;
    o.w = (float)((a.y >> 4) - 8) * s;
}

__global__ __launch_bounds__(256) void int4_dequant_kernel(
    const v2i* __restrict__ packed,    // NQUADS 8B chunks (8 nibbles each)
    const float* __restrict__ scale,   // 4096*86 flat, one per 32 quads
    v4f* __restrict__ out)             // NQUADS float4s
{
    const int t = blockIdx.x * 256 + threadIdx.x;
    const int lane = t & 63;
    const int q0 = ((t & ~63) << 1) + lane;  // wave_base*2 + lane
    const int q1 = q0 + 64;

    v2i a = packed[q0];
    v2i b = packed[q1];
    const float s0 = scale[q0 >> 5];
    const float s1 = scale[q1 >> 5];

    v4f o0, o1;
    dequant8(a, s0, o0);
    dequant8(b, s1, o1);

    out[q0] = o0;
    out[q1] = o1;
}

extern "C" void kernel_launch(void* const* d_in, const int* in_sizes, int n_in,
                              void* d_out, int out_size, void* d_ws, size_t ws_size,
                              hipStream_t stream) {
    const v2i*   packed = (const v2i*)d_in[0];
    const float* scale  = (const float*)d_in[1];
    v4f*         out    = (v4f*)d_out;

    int4_dequant_kernel<<<NBLOCKS, 256, 0, stream>>>(packed, scale, out);
}

// Round 6
// 235.286 us; speedup vs baseline: 1.2253x; 1.0371x over previous
//
#include <hip/hip_runtime.h>

// INT4 symmetric weight dequant: packed uint8-in-int32 nibbles -> fp32,
// per-(row,group) scale. OUT=4096, GROUPS=86, GSIZE=128.
//
// FINAL (R6 = R3 kernel): non-temporal loads+stores, contiguous layout.
// Three-point timing solve (R3/R4/R5): K_nt = 44.3 us, K_cached = 52.9 us,
// harness C = 191.1 us. nt wins: 272 MB of zero-reuse streams shouldn't
// allocate in LLC (write-backs would contend with the read stream).
// K_nt = 272 MB / 44.3 us = 6.14 TB/s combined = ~94-97% of achievable
// ceiling -> memory roofline.
//
// Layout: every memory instruction perfectly contiguous across the wave:
// lane l handles quads (wave_base + l) and (wave_base + 64 + l).
// Each quad's 4 outputs share one scale (128-elem groups = 32 quads);
// 32 consecutive lanes share a scale load -> L1-served, negligible traffic.

#define TOTAL_ELEMS (4096 * 86 * 128)        // 45,088,768
#define NQUADS (TOTAL_ELEMS / 4)             // 11,272,192 float4s
#define NTHREADS (NQUADS / 2)                // 5,636,096
#define NBLOCKS (NTHREADS / 256)             // 22016 exactly

typedef int   v2i __attribute__((ext_vector_type(2)));
typedef float v4f __attribute__((ext_vector_type(4)));

__device__ __forceinline__ void dequant8(v2i a, float s, v4f& o) {
    o.x = (float)((a.x & 15) - 8) * s;
    o.y = (float)((a.x >> 4) - 8) * s;
    o.z = (float)((a.y & 15) - 8) * s;
    o.w = (float)((a.y >> 4) - 8) * s;
}

__global__ __launch_bounds__(256) void int4_dequant_kernel(
    const v2i* __restrict__ packed,    // NQUADS 8B chunks (8 nibbles each)
    const float* __restrict__ scale,   // 4096*86 flat, one per 32 quads
    v4f* __restrict__ out)             // NQUADS float4s
{
    const int t = blockIdx.x * 256 + threadIdx.x;
    const int lane = t & 63;
    const int q0 = ((t & ~63) << 1) + lane;  // wave_base*2 + lane
    const int q1 = q0 + 64;

    v2i a = __builtin_nontemporal_load(&packed[q0]);
    v2i b = __builtin_nontemporal_load(&packed[q1]);
    const float s0 = scale[q0 >> 5];
    const float s1 = scale[q1 >> 5];

    v4f o0, o1;
    dequant8(a, s0, o0);
    dequant8(b, s1, o1);

    __builtin_nontemporal_store(o0, &out[q0]);
    __builtin_nontemporal_store(o1, &out[q1]);
}

extern "C" void kernel_launch(void* const* d_in, const int* in_sizes, int n_in,
                              void* d_out, int out_size, void* d_ws, size_t ws_size,
                              hipStream_t stream) {
    const v2i*   packed = (const v2i*)d_in[0];
    const float* scale  = (const float*)d_in[1];
    v4f*         out    = (v4f*)d_out;

    int4_dequant_kernel<<<NBLOCKS, 256, 0, stream>>>(packed, scale, out);
}